// Round 1
// baseline (361.691 us; speedup 1.0000x reference)
//
#include <hip/hip_runtime.h>
#include <hip/hip_bf16.h>

// Problem constants
#define B_   16
#define N_   1024
#define C_   768
#define H_   12
#define HD_  64
#define M_   16384   // B*N tokens
#define N1_  2304    // 3*C
#define NEG_BIG (-1e30f)

typedef __attribute__((ext_vector_type(8))) short bf16x8;   // 8 bf16 = 4 VGPR
typedef __attribute__((ext_vector_type(4))) float f32x4;

// ---- bf16 helpers via raw bits (avoid __hip_bfloat16 struct in unions) ----
__device__ __forceinline__ unsigned short f2bf(float f) {
  unsigned int u = __float_as_uint(f);
  u = u + 0x7fffu + ((u >> 16) & 1u);   // round-to-nearest-even
  return (unsigned short)(u >> 16);
}
__device__ __forceinline__ float bf2f(unsigned short h) {
  return __uint_as_float(((unsigned int)h) << 16);
}

__device__ __forceinline__ void gload_lds16(const void* g, void* l) {
  __builtin_amdgcn_global_load_lds(
      (const __attribute__((address_space(1))) void*)g,
      (__attribute__((address_space(3))) void*)l, 16, 0, 0);
}

// =====================================================================
// Prep kernels
// =====================================================================

// x fp32 -> bf16, 8 elems/thread
__global__ __launch_bounds__(256) void k_cvt_x(const float* __restrict__ x,
                                               unsigned short* __restrict__ xb) {
  long i = ((long)blockIdx.x * 256 + threadIdx.x) * 8;
  float4 a = *(const float4*)(x + i);
  float4 b = *(const float4*)(x + i + 4);
  bf16x8 v;
  v[0] = (short)f2bf(a.x); v[1] = (short)f2bf(a.y);
  v[2] = (short)f2bf(a.z); v[3] = (short)f2bf(a.w);
  v[4] = (short)f2bf(b.x); v[5] = (short)f2bf(b.y);
  v[6] = (short)f2bf(b.z); v[7] = (short)f2bf(b.w);
  *(bf16x8*)(xb + i) = v;
}

// Wqkv [768,2304] fp32 -> WqkvT [2304,768] bf16   (B^T layout for GEMM)
__global__ __launch_bounds__(256) void k_prep_wqkvT(const float* __restrict__ W,
                                                    unsigned short* __restrict__ Wt) {
  int tid = blockIdx.x * 256 + threadIdx.x;   // 96*2304 threads
  int n  = tid % N1_;
  int kc = tid / N1_;                          // 0..95
  bf16x8 v;
#pragma unroll
  for (int j = 0; j < 8; ++j)
    v[j] = (short)f2bf(W[(long)(kc * 8 + j) * N1_ + n]);
  *(bf16x8*)(Wt + (long)n * C_ + kc * 8) = v;
}

// Wout [768,768] fp32 -> Wt3 [768 n][2304 k'] bf16 with k' blocks [hi, hi, lo]
__global__ __launch_bounds__(256) void k_prep_wout(const float* __restrict__ W,
                                                   unsigned short* __restrict__ Wt3) {
  int tid = blockIdx.x * 256 + threadIdx.x;   // 96*768 threads
  int n  = tid % C_;
  int kc = tid / C_;                           // 0..95
  bf16x8 hi, lo;
#pragma unroll
  for (int j = 0; j < 8; ++j) {
    float wv = W[(long)(kc * 8 + j) * C_ + n];
    unsigned short h = f2bf(wv);
    hi[j] = (short)h;
    lo[j] = (short)f2bf(wv - bf2f(h));
  }
  unsigned short* base = Wt3 + (long)n * N1_ + kc * 8;
  *(bf16x8*)(base)        = hi;
  *(bf16x8*)(base + 768)  = hi;
  *(bf16x8*)(base + 1536) = lo;
}

// Transpose V region of qkvb into Vt [bh][64 d][1024 n]
__global__ __launch_bounds__(256) void k_transposeV(const unsigned short* __restrict__ qkvb,
                                                    unsigned short* __restrict__ Vt) {
  int bh   = blockIdx.x >> 5;   // 0..191
  int nblk = blockIdx.x & 31;
  int b = bh / H_, h = bh % H_;
  int t = threadIdx.x;
  int nl = t >> 3, dc = t & 7;
  long token = (long)b * N_ + nblk * 32 + nl;
  bf16x8 v = *(const bf16x8*)(qkvb + token * N1_ + 1536 + h * HD_ + dc * 8);
#pragma unroll
  for (int j = 0; j < 8; ++j)
    Vt[((long)bh * HD_ + dc * 8 + j) * N_ + nblk * 32 + nl] = (unsigned short)v[j];
}

// =====================================================================
// GEMM: C[M,N] = A[M,K](bf16) * Bt[N,K]^T(bf16) + bias
// STAGE 1: out = qkvb bf16 (cols<768 scaled by 1/8);  STAGE 3: out = fp32
// 128x128 tile, BK=64, 4 waves, global_load_lds w/ pre-swizzled source
// =====================================================================
template <int STAGE>
__global__ __launch_bounds__(256)
void gemm_bf16(const unsigned short* __restrict__ A,
               const unsigned short* __restrict__ Bt,
               const float* __restrict__ bias,
               void* __restrict__ out, int Kdim, int Ndim) {
  __shared__ unsigned char lds[32768];   // A tile 16K | B tile 16K
  const int t = threadIdx.x;
  const int l = t & 63, w = t >> 6;
  const int g = l >> 4, lr = l & 15;
  const int NB = Ndim >> 7;
  const int mb = blockIdx.x / NB, nb = blockIdx.x % NB;
  const long m0 = (long)mb << 7, n0 = (long)nb << 7;
  const int wm = w >> 1, wn = w & 1;

  f32x4 acc[4][4];
  const f32x4 zz = {0.f, 0.f, 0.f, 0.f};
#pragma unroll
  for (int i = 0; i < 4; ++i)
#pragma unroll
    for (int j = 0; j < 4; ++j) acc[i][j] = zz;

  // staging slot decode: slot s = i*4096 + t*16 ; LDS linear, swizzled SOURCE
  int srow[4], sx[4];
#pragma unroll
  for (int i = 0; i < 4; ++i) {
    int s = i * 4096 + t * 16;
    int row = s >> 7;
    srow[i] = row;
    sx[i] = (s & 127) ^ ((row & 7) << 4);
  }
  const char* Ab = (const char*)A;
  const char* Bb = (const char*)Bt;
  const int wbase = (t & 192) * 16;   // wave-uniform LDS base (w*1024)

  for (int kt = 0; kt < Kdim; kt += 64) {
#pragma unroll
    for (int i = 0; i < 4; ++i) {
      const char* src = Ab + ((m0 + srow[i]) * Kdim + kt) * 2 + sx[i];
      gload_lds16(src, (void*)(lds + i * 4096 + wbase));
    }
#pragma unroll
    for (int i = 0; i < 4; ++i) {
      const char* src = Bb + ((n0 + srow[i]) * Kdim + kt) * 2 + sx[i];
      gload_lds16(src, (void*)(lds + 16384 + i * 4096 + wbase));
    }
    __syncthreads();
#pragma unroll
    for (int ks = 0; ks < 2; ++ks) {
      bf16x8 af[4], bfr[4];
#pragma unroll
      for (int mi = 0; mi < 4; ++mi) {
        int row = wm * 64 + mi * 16 + lr;
        int off = row * 128 + ((ks * 64 + g * 16) ^ ((row & 7) << 4));
        af[mi] = *(const bf16x8*)(lds + off);
      }
#pragma unroll
      for (int ni = 0; ni < 4; ++ni) {
        int row = wn * 64 + ni * 16 + lr;
        int off = 16384 + row * 128 + ((ks * 64 + g * 16) ^ ((row & 7) << 4));
        bfr[ni] = *(const bf16x8*)(lds + off);
      }
#pragma unroll
      for (int mi = 0; mi < 4; ++mi)
#pragma unroll
        for (int ni = 0; ni < 4; ++ni)
          acc[mi][ni] = __builtin_amdgcn_mfma_f32_16x16x32_bf16(
              af[mi], bfr[ni], acc[mi][ni], 0, 0, 0);
    }
    __syncthreads();
  }

  // epilogue: D-frag col = lane&15, row = (lane>>4)*4 + r
#pragma unroll
  for (int ni = 0; ni < 4; ++ni) {
    int col = (int)n0 + wn * 64 + ni * 16 + lr;
    float bv = bias[col];
    if (STAGE == 1) {
      float sc = (col < 768) ? 0.125f : 1.0f;   // pre-scale Q by 1/sqrt(HD)
      unsigned short* o = (unsigned short*)out;
#pragma unroll
      for (int mi = 0; mi < 4; ++mi)
#pragma unroll
        for (int r = 0; r < 4; ++r) {
          long rowm = m0 + wm * 64 + mi * 16 + g * 4 + r;
          o[rowm * N1_ + col] = f2bf((acc[mi][ni][r] + bv) * sc);
        }
    } else {
      float* o = (float*)out;
#pragma unroll
      for (int mi = 0; mi < 4; ++mi)
#pragma unroll
        for (int r = 0; r < 4; ++r) {
          long rowm = m0 + wm * 64 + mi * 16 + g * 4 + r;
          o[rowm * C_ + col] = acc[mi][ni][r] + bv;
        }
    }
  }
}

// =====================================================================
// Fused flash attention. Block = 4 waves x 32 q-rows = 128 q.
// grid = 192 heads * 8 qblocks. K,V tiles (64 kv) staged via gload_lds.
// Writes O split [hi | lo | hi] into Osp [16384][2304] for stage-3 GEMM.
// =====================================================================
__global__ __launch_bounds__(256)
void attn_fused(const unsigned short* __restrict__ qkvb,
                const unsigned short* __restrict__ Vt,
                unsigned short* __restrict__ Osp) {
  __shared__ unsigned char lds[32768];  // K 8K | V 8K | P 4 waves * 4K
  const int t = threadIdx.x, l = t & 63, w = t >> 6;
  const int g = l >> 4, lr = l & 15;
  const int bh = blockIdx.x >> 3, qb = blockIdx.x & 7;
  const int b = bh / H_, h = bh % H_;
  const long tok0 = (long)b * N_;
  const int q0 = qb * 128 + w * 32;

  // Q fragments (Q was pre-scaled by 1/8 in stage-1 epilogue)
  bf16x8 qa[2][2];
#pragma unroll
  for (int mi = 0; mi < 2; ++mi)
#pragma unroll
    for (int ks = 0; ks < 2; ++ks)
      qa[mi][ks] = *(const bf16x8*)(qkvb + (tok0 + q0 + mi * 16 + lr) * N1_ +
                                    h * HD_ + ks * 32 + g * 8);

  const f32x4 zz = {0.f, 0.f, 0.f, 0.f};
  f32x4 o[2][4];
  float mrun[2][4], lrun[2][4];
#pragma unroll
  for (int mi = 0; mi < 2; ++mi) {
#pragma unroll
    for (int df = 0; df < 4; ++df) o[mi][df] = zz;
#pragma unroll
    for (int r = 0; r < 4; ++r) { mrun[mi][r] = NEG_BIG; lrun[mi][r] = 0.f; }
  }

  unsigned char* Pl = lds + 16384 + w * 4096;
  int srow[2], sx[2];
#pragma unroll
  for (int i = 0; i < 2; ++i) {
    int s = i * 4096 + t * 16;
    int row = s >> 7;
    srow[i] = row;
    sx[i] = (s & 127) ^ ((row & 7) << 4);
  }
  const char* Vg = (const char*)(Vt + (long)bh * HD_ * N_);
  const int wbase = (t & 192) * 16;

  for (int kv0 = 0; kv0 < N_; kv0 += 64) {
    // stage K tile [64 kv][64 k] and V tile [64 d][64 kv] (from Vt rows)
#pragma unroll
    for (int i = 0; i < 2; ++i) {
      const char* src = (const char*)qkvb +
          ((tok0 + kv0 + srow[i]) * N1_ + C_ + h * HD_) * 2 + sx[i];
      gload_lds16(src, (void*)(lds + i * 4096 + wbase));
    }
#pragma unroll
    for (int i = 0; i < 2; ++i) {
      const char* src = Vg + ((long)srow[i] * N_ + kv0) * 2 + sx[i];
      gload_lds16(src, (void*)(lds + 8192 + i * 4096 + wbase));
    }
    __syncthreads();

    // S = Q K^T  (pre-scaled)
    f32x4 s4[2][4];
    {
      bf16x8 kb0[4], kb1[4];
#pragma unroll
      for (int f = 0; f < 4; ++f) {
        int row = f * 16 + lr;
        kb0[f] = *(const bf16x8*)(lds + row * 128 + ((g * 16) ^ ((row & 7) << 4)));
        kb1[f] = *(const bf16x8*)(lds + row * 128 + ((64 + g * 16) ^ ((row & 7) << 4)));
      }
#pragma unroll
      for (int mi = 0; mi < 2; ++mi)
#pragma unroll
        for (int f = 0; f < 4; ++f) {
          f32x4 s = __builtin_amdgcn_mfma_f32_16x16x32_bf16(qa[mi][0], kb0[f], zz, 0, 0, 0);
          s = __builtin_amdgcn_mfma_f32_16x16x32_bf16(qa[mi][1], kb1[f], s, 0, 0, 0);
          s4[mi][f] = s;
        }
    }

    // online softmax (stats per q-row; lane holds rows q = mi*16 + g*4 + r)
#pragma unroll
    for (int mi = 0; mi < 2; ++mi) {
      float cmax[4], rsum[4], alpha[4];
#pragma unroll
      for (int r = 0; r < 4; ++r)
        cmax[r] = fmaxf(fmaxf(s4[mi][0][r], s4[mi][1][r]),
                        fmaxf(s4[mi][2][r], s4[mi][3][r]));
#pragma unroll
      for (int d = 1; d < 16; d <<= 1)
#pragma unroll
        for (int r = 0; r < 4; ++r)
          cmax[r] = fmaxf(cmax[r], __shfl_xor(cmax[r], d));
#pragma unroll
      for (int r = 0; r < 4; ++r) {
        float mn = fmaxf(mrun[mi][r], cmax[r]);
        alpha[r] = __expf(mrun[mi][r] - mn);   // exp(-1e30) = 0 on first tile
        mrun[mi][r] = mn;
        rsum[r] = 0.f;
      }
#pragma unroll
      for (int f = 0; f < 4; ++f)
#pragma unroll
        for (int r = 0; r < 4; ++r) {
          float p = __expf(s4[mi][f][r] - mrun[mi][r]);
          rsum[r] += p;
          int q = mi * 16 + g * 4 + r;
          int off = ((q * 64 + f * 16 + lr) * 2) ^ ((q & 7) << 4);
          *(unsigned short*)(Pl + off) = f2bf(p);
        }
#pragma unroll
      for (int d = 1; d < 16; d <<= 1)
#pragma unroll
        for (int r = 0; r < 4; ++r)
          rsum[r] += __shfl_xor(rsum[r], d);
#pragma unroll
      for (int r = 0; r < 4; ++r)
        lrun[mi][r] = lrun[mi][r] * alpha[r] + rsum[r];
#pragma unroll
      for (int df = 0; df < 4; ++df)
#pragma unroll
        for (int r = 0; r < 4; ++r)
          o[mi][df][r] *= alpha[r];
    }

    // O += P V   (P from per-wave LDS, V from swizzled V tile)
#pragma unroll
    for (int ks = 0; ks < 2; ++ks) {
      bf16x8 pa[2], vb[4];
#pragma unroll
      for (int mi = 0; mi < 2; ++mi) {
        int q = mi * 16 + lr;
        int off = ((q * 64 + ks * 32 + g * 8) * 2) ^ ((q & 7) << 4);
        pa[mi] = *(const bf16x8*)(Pl + off);
      }
#pragma unroll
      for (int df = 0; df < 4; ++df) {
        int d = df * 16 + lr;
        int off = 8192 + d * 128 + ((ks * 64 + g * 16) ^ ((d & 7) << 4));
        vb[df] = *(const bf16x8*)(lds + off);
      }
#pragma unroll
      for (int mi = 0; mi < 2; ++mi)
#pragma unroll
        for (int df = 0; df < 4; ++df)
          o[mi][df] = __builtin_amdgcn_mfma_f32_16x16x32_bf16(pa[mi], vb[df], o[mi][df], 0, 0, 0);
    }
    __syncthreads();
  }

  // epilogue: normalize, split hi/lo, write Osp blocks [hi | lo | hi]
#pragma unroll
  for (int mi = 0; mi < 2; ++mi) {
    float inv[4];
#pragma unroll
    for (int r = 0; r < 4; ++r) inv[r] = 1.0f / lrun[mi][r];
#pragma unroll
    for (int df = 0; df < 4; ++df)
#pragma unroll
      for (int r = 0; r < 4; ++r) {
        float v = o[mi][df][r] * inv[r];
        long token = tok0 + q0 + mi * 16 + g * 4 + r;
        int c = h * HD_ + df * 16 + lr;
        unsigned short hi = f2bf(v);
        unsigned short lo = f2bf(v - bf2f(hi));
        Osp[token * N1_ + c] = hi;
        Osp[token * N1_ + 768 + c] = lo;
        Osp[token * N1_ + 1536 + c] = hi;
      }
  }
}

// =====================================================================
extern "C" void kernel_launch(void* const* d_in, const int* in_sizes, int n_in,
                              void* d_out, int out_size, void* d_ws, size_t ws_size,
                              hipStream_t stream) {
  const float* x    = (const float*)d_in[0];
  const float* Wqkv = (const float*)d_in[1];
  const float* bqkv = (const float*)d_in[2];
  const float* Wout = (const float*)d_in[3];
  const float* bout = (const float*)d_in[4];

  char* ws = (char*)d_ws;
  unsigned short* qkvb  = (unsigned short*)(ws);                 // 75,497,472 B
  unsigned short* Osp   = (unsigned short*)(ws + 75497472L);     // 75,497,472 B
  unsigned short* xb    = (unsigned short*)(ws + 150994944L);    // 25,165,824 B
  unsigned short* Vt    = (unsigned short*)(ws + 150994944L);    // alias of xb (xb dead by then)
  unsigned short* WqkvT = (unsigned short*)(ws + 176160768L);    //  3,538,944 B
  unsigned short* Wt3   = (unsigned short*)(ws + 179699712L);    //  3,538,944 B
  // total: 183,238,656 B

  k_cvt_x<<<6144, 256, 0, stream>>>(x, xb);
  k_prep_wqkvT<<<864, 256, 0, stream>>>(Wqkv, WqkvT);
  k_prep_wout<<<288, 256, 0, stream>>>(Wout, Wt3);
  gemm_bf16<1><<<128 * 18, 256, 0, stream>>>(xb, WqkvT, bqkv, (void*)qkvb, 768, 2304);
  k_transposeV<<<6144, 256, 0, stream>>>(qkvb, Vt);
  attn_fused<<<1536, 256, 0, stream>>>(qkvb, Vt, Osp);
  gemm_bf16<3><<<128 * 6, 256, 0, stream>>>(Osp, Wt3, bout, d_out, 2304, 768);
}

// Round 2
// 285.010 us; speedup vs baseline: 1.2690x; 1.2690x over previous
//
#include <hip/hip_runtime.h>
#include <hip/hip_bf16.h>

// Problem constants
#define B_   16
#define N_   1024
#define C_   768
#define H_   12
#define HD_  64
#define M_   16384   // B*N tokens
#define N1_  2304    // 3*C
#define NEG_BIG (-1e30f)

typedef __attribute__((ext_vector_type(8))) short bf16x8;   // 8 bf16 = 4 VGPR
typedef __attribute__((ext_vector_type(4))) float f32x4;

// ---- bf16 helpers via raw bits ----
__device__ __forceinline__ unsigned short f2bf(float f) {
  unsigned int u = __float_as_uint(f);
  u = u + 0x7fffu + ((u >> 16) & 1u);   // round-to-nearest-even
  return (unsigned short)(u >> 16);
}
__device__ __forceinline__ float bf2f(unsigned short h) {
  return __uint_as_float(((unsigned int)h) << 16);
}
__device__ __forceinline__ unsigned int cvtpk_bf16(float a, float b) {
  unsigned int r;
  asm("v_cvt_pk_bf16_f32 %0, %1, %2" : "=v"(r) : "v"(a), "v"(b));
  return r;  // lo16 = bf16(a), hi16 = bf16(b)
}

__device__ __forceinline__ void gload_lds16(const void* g, void* l) {
  __builtin_amdgcn_global_load_lds(
      (const __attribute__((address_space(1))) void*)g,
      (__attribute__((address_space(3))) void*)l, 16, 0, 0);
}

// =====================================================================
// Prep kernels
// =====================================================================

__global__ __launch_bounds__(256) void k_cvt_x(const float* __restrict__ x,
                                               unsigned short* __restrict__ xb) {
  long i = ((long)blockIdx.x * 256 + threadIdx.x) * 8;
  float4 a = *(const float4*)(x + i);
  float4 b = *(const float4*)(x + i + 4);
  bf16x8 v;
  v[0] = (short)f2bf(a.x); v[1] = (short)f2bf(a.y);
  v[2] = (short)f2bf(a.z); v[3] = (short)f2bf(a.w);
  v[4] = (short)f2bf(b.x); v[5] = (short)f2bf(b.y);
  v[6] = (short)f2bf(b.z); v[7] = (short)f2bf(b.w);
  *(bf16x8*)(xb + i) = v;
}

__global__ __launch_bounds__(256) void k_prep_wqkvT(const float* __restrict__ W,
                                                    unsigned short* __restrict__ Wt) {
  int tid = blockIdx.x * 256 + threadIdx.x;   // 96*2304 threads
  int n  = tid % N1_;
  int kc = tid / N1_;                          // 0..95
  bf16x8 v;
#pragma unroll
  for (int j = 0; j < 8; ++j)
    v[j] = (short)f2bf(W[(long)(kc * 8 + j) * N1_ + n]);
  *(bf16x8*)(Wt + (long)n * C_ + kc * 8) = v;
}

__global__ __launch_bounds__(256) void k_prep_wout(const float* __restrict__ W,
                                                   unsigned short* __restrict__ Wt3) {
  int tid = blockIdx.x * 256 + threadIdx.x;   // 96*768 threads
  int n  = tid % C_;
  int kc = tid / C_;                           // 0..95
  bf16x8 hi, lo;
#pragma unroll
  for (int j = 0; j < 8; ++j) {
    float wv = W[(long)(kc * 8 + j) * C_ + n];
    unsigned short h = f2bf(wv);
    hi[j] = (short)h;
    lo[j] = (short)f2bf(wv - bf2f(h));
  }
  unsigned short* base = Wt3 + (long)n * N1_ + kc * 8;
  *(bf16x8*)(base)        = hi;
  *(bf16x8*)(base + 768)  = hi;
  *(bf16x8*)(base + 1536) = lo;
}

// Transpose V region of qkvb into Vt [bh][64 d][1024 n] via LDS tile.
// Block handles [128 n x 64 d]. XOR-swizzled LDS (byte ^= ((d>>3)&7)<<4).
__global__ __launch_bounds__(256) void k_transposeV2(const unsigned short* __restrict__ qkvb,
                                                     unsigned short* __restrict__ Vt) {
  __shared__ unsigned char lt[16384];   // [64 d][128 n] bf16, swizzled
  int wid = (blockIdx.x & 7) * 192 + (blockIdx.x >> 3);   // XCD-chunked
  int bh = wid >> 3, nb = wid & 7;
  int b = bh / H_, h = bh % H_;
  long tok0 = (long)b * N_ + nb * 128;
  int t = threadIdx.x;
  int d0 = (t & 7) * 8;
#pragma unroll
  for (int it = 0; it < 4; ++it) {
    int nl = it * 32 + (t >> 3);
    bf16x8 v = *(const bf16x8*)(qkvb + (tok0 + nl) * N1_ + 1536 + h * HD_ + d0);
#pragma unroll
    for (int j = 0; j < 8; ++j) {
      int d = d0 + j;
      *(unsigned short*)(lt + d * 256 + ((nl * 2) ^ (((d >> 3) & 7) << 4))) =
          (unsigned short)v[j];
    }
  }
  __syncthreads();
  int l = t & 63, wv = t >> 6;
  int p = l & 1;
  int dbase = ((l >> 1) & 7) * 8 + (l >> 4) * 2;
#pragma unroll
  for (int rr = 0; rr < 4; ++rr) {
    int d = dbase + (rr & 1);
    int n0 = wv * 32 + (rr >> 1) * 16 + p * 8;
    bf16x8 v = *(const bf16x8*)(lt + d * 256 + ((n0 * 2) ^ (((d >> 3) & 7) << 4)));
    *(bf16x8*)(Vt + ((long)bh * HD_ + d) * N_ + nb * 128 + n0) = v;
  }
}

// =====================================================================
// GEMM: C[M,N] = A[M,K](bf16) * Bt[N,K]^T(bf16) + bias   (unchanged)
// =====================================================================
template <int STAGE>
__global__ __launch_bounds__(256)
void gemm_bf16(const unsigned short* __restrict__ A,
               const unsigned short* __restrict__ Bt,
               const float* __restrict__ bias,
               void* __restrict__ out, int Kdim, int Ndim) {
  __shared__ unsigned char lds[32768];   // A tile 16K | B tile 16K
  const int t = threadIdx.x;
  const int l = t & 63, w = t >> 6;
  const int g = l >> 4, lr = l & 15;
  const int NB = Ndim >> 7;
  const int mb = blockIdx.x / NB, nb = blockIdx.x % NB;
  const long m0 = (long)mb << 7, n0 = (long)nb << 7;
  const int wm = w >> 1, wn = w & 1;

  f32x4 acc[4][4];
  const f32x4 zz = {0.f, 0.f, 0.f, 0.f};
#pragma unroll
  for (int i = 0; i < 4; ++i)
#pragma unroll
    for (int j = 0; j < 4; ++j) acc[i][j] = zz;

  int srow[4], sx[4];
#pragma unroll
  for (int i = 0; i < 4; ++i) {
    int s = i * 4096 + t * 16;
    int row = s >> 7;
    srow[i] = row;
    sx[i] = (s & 127) ^ ((row & 7) << 4);
  }
  const char* Ab = (const char*)A;
  const char* Bb = (const char*)Bt;
  const int wbase = (t & 192) * 16;

  for (int kt = 0; kt < Kdim; kt += 64) {
#pragma unroll
    for (int i = 0; i < 4; ++i) {
      const char* src = Ab + ((m0 + srow[i]) * Kdim + kt) * 2 + sx[i];
      gload_lds16(src, (void*)(lds + i * 4096 + wbase));
    }
#pragma unroll
    for (int i = 0; i < 4; ++i) {
      const char* src = Bb + ((n0 + srow[i]) * Kdim + kt) * 2 + sx[i];
      gload_lds16(src, (void*)(lds + 16384 + i * 4096 + wbase));
    }
    __syncthreads();
#pragma unroll
    for (int ks = 0; ks < 2; ++ks) {
      bf16x8 af[4], bfr[4];
#pragma unroll
      for (int mi = 0; mi < 4; ++mi) {
        int row = wm * 64 + mi * 16 + lr;
        int off = row * 128 + ((ks * 64 + g * 16) ^ ((row & 7) << 4));
        af[mi] = *(const bf16x8*)(lds + off);
      }
#pragma unroll
      for (int ni = 0; ni < 4; ++ni) {
        int row = wn * 64 + ni * 16 + lr;
        int off = 16384 + row * 128 + ((ks * 64 + g * 16) ^ ((row & 7) << 4));
        bfr[ni] = *(const bf16x8*)(lds + off);
      }
#pragma unroll
      for (int mi = 0; mi < 4; ++mi)
#pragma unroll
        for (int ni = 0; ni < 4; ++ni)
          acc[mi][ni] = __builtin_amdgcn_mfma_f32_16x16x32_bf16(
              af[mi], bfr[ni], acc[mi][ni], 0, 0, 0);
    }
    __syncthreads();
  }

#pragma unroll
  for (int ni = 0; ni < 4; ++ni) {
    int col = (int)n0 + wn * 64 + ni * 16 + lr;
    float bv = bias[col];
    if (STAGE == 1) {
      float sc = (col < 768) ? 0.125f : 1.0f;   // pre-scale Q by 1/sqrt(HD)
      unsigned short* o = (unsigned short*)out;
#pragma unroll
      for (int mi = 0; mi < 4; ++mi)
#pragma unroll
        for (int r = 0; r < 4; ++r) {
          long rowm = m0 + wm * 64 + mi * 16 + g * 4 + r;
          o[rowm * N1_ + col] = f2bf((acc[mi][ni][r] + bv) * sc);
        }
    } else {
      float* o = (float*)out;
#pragma unroll
      for (int mi = 0; mi < 4; ++mi)
#pragma unroll
        for (int r = 0; r < 4; ++r) {
          long rowm = m0 + wm * 64 + mi * 16 + g * 4 + r;
          o[rowm * C_ + col] = acc[mi][ni][r] + bv;
        }
    }
  }
}

// =====================================================================
// Fused flash attention, swapped-QK^T (in-register softmax).
// 4 waves x 32 q-rows = 128 q per block; KV tiles of 64, double-buffered
// via gload_lds + counted vmcnt + raw barriers. P never touches LDS.
// =====================================================================
__global__ __launch_bounds__(256, 3)
void attn_fused(const unsigned short* __restrict__ qkvb,
                const unsigned short* __restrict__ Vt,
                unsigned short* __restrict__ Osp) {
  __shared__ unsigned char lds[32768];  // 2 x (K 8K | V 8K)
  const int t = threadIdx.x, l = t & 63, w = t >> 6;
  const int gg = l >> 4, lrq = l & 15;
  // XCD-chunked swizzle: 8 q-blocks of one head share one XCD's L2
  const int wid = (blockIdx.x & 7) * 192 + (blockIdx.x >> 3);
  const int bh = wid >> 3, qb = wid & 7;
  const int b = bh / H_, h = bh % H_;
  const long tok0 = (long)b * N_;
  const int q0 = qb * 128 + w * 32;

  // Q fragments (pre-scaled by 1/8 in stage-1). B-operand: col=q, k=c.
  bf16x8 qa[2][2];
#pragma unroll
  for (int mi = 0; mi < 2; ++mi)
#pragma unroll
    for (int ks = 0; ks < 2; ++ks)
      qa[mi][ks] = *(const bf16x8*)(qkvb + (tok0 + q0 + mi * 16 + lrq) * N1_ +
                                    h * HD_ + ks * 32 + gg * 8);

  const f32x4 zz = {0.f, 0.f, 0.f, 0.f};
  f32x4 o[2][4];
  float mrun[2], lrun[2];
#pragma unroll
  for (int mi = 0; mi < 2; ++mi) {
#pragma unroll
    for (int df = 0; df < 4; ++df) o[mi][df] = zz;
    mrun[mi] = NEG_BIG; lrun[mi] = 0.f;
  }

  // staging decode (slot s = i*4096 + t*16; source pre-swizzled)
  const int sxs = ((t & 7) * 16) ^ (((t >> 3) & 7) << 4);
  const int wbase = (t & 192) * 16;
  const char* Vg = (const char*)(Vt + (long)bh * HD_ * N_);
  const char* Kg = (const char*)qkvb + ((tok0)*N1_ + C_ + h * HD_) * 2;

#define STAGE_KV(kv0, buf)                                                  \
  {                                                                         \
    _Pragma("unroll")                                                       \
    for (int i = 0; i < 2; ++i) {                                           \
      int row = i * 32 + (t >> 3);                                          \
      gload_lds16(Kg + ((long)(kv0 + row) * N1_) * 2 + sxs,                 \
                  (void*)((buf) + i * 4096 + wbase));                       \
    }                                                                       \
    _Pragma("unroll")                                                       \
    for (int i = 0; i < 2; ++i) {                                           \
      int row = i * 32 + (t >> 3);                                          \
      gload_lds16(Vg + ((long)row * N_ + (kv0)) * 2 + sxs,                  \
                  (void*)((buf) + 8192 + i * 4096 + wbase));                \
    }                                                                       \
  }

  STAGE_KV(0, lds);

#pragma unroll 2
  for (int tt = 0; tt < 16; ++tt) {
    unsigned char* curb = lds + (tt & 1) * 16384;
    unsigned char* nxtb = lds + ((tt & 1) ^ 1) * 16384;
    if (tt < 15) {
      STAGE_KV((tt + 1) * 64, nxtb);
      asm volatile("s_waitcnt vmcnt(4)" ::: "memory");
    } else {
      asm volatile("s_waitcnt vmcnt(0)" ::: "memory");
    }
    __builtin_amdgcn_s_barrier();
    __builtin_amdgcn_sched_barrier(0);

    // ---- S^T = mfma(K, Q): lane holds 16 scores of its OWN q-row ----
    f32x4 st[2][4];
    {
      bf16x8 kf[4][2];
#pragma unroll
      for (int f = 0; f < 4; ++f)
#pragma unroll
        for (int ks = 0; ks < 2; ++ks) {
          int row = f * 16 + lrq;
          kf[f][ks] = *(const bf16x8*)(curb + row * 128 +
                                       ((ks * 64 + gg * 16) ^ ((row & 7) << 4)));
        }
#pragma unroll
      for (int mi = 0; mi < 2; ++mi)
#pragma unroll
        for (int f = 0; f < 4; ++f) {
          f32x4 s = __builtin_amdgcn_mfma_f32_16x16x32_bf16(kf[f][0], qa[mi][0], zz, 0, 0, 0);
          st[mi][f] = __builtin_amdgcn_mfma_f32_16x16x32_bf16(kf[f][1], qa[mi][1], s, 0, 0, 0);
        }
    }

    // ---- online softmax (in-lane + 2 shfl) + pack + lane exchange ----
    bf16x8 paM[2][2];
#pragma unroll
    for (int mi = 0; mi < 2; ++mi) {
      float mx = st[mi][0][0];
#pragma unroll
      for (int f = 0; f < 4; ++f)
#pragma unroll
        for (int r = 0; r < 4; ++r) mx = fmaxf(mx, st[mi][f][r]);
      mx = fmaxf(mx, __shfl_xor(mx, 16));
      mx = fmaxf(mx, __shfl_xor(mx, 32));
      float mn = fmaxf(mrun[mi], mx);
      float alpha = __expf(mrun[mi] - mn);
      mrun[mi] = mn;
      float rs = 0.f;
      float p[4][4];
#pragma unroll
      for (int f = 0; f < 4; ++f)
#pragma unroll
        for (int r = 0; r < 4; ++r) {
          p[f][r] = __expf(st[mi][f][r] - mn);
          rs += p[f][r];
        }
      rs += __shfl_xor(rs, 16);
      rs += __shfl_xor(rs, 32);
      lrun[mi] = lrun[mi] * alpha + rs;
      // rescale O: row r holds q = mi*16 + gg*4 + r -> pull that q's alpha
#pragma unroll
      for (int r = 0; r < 4; ++r) {
        float ar = __shfl(alpha, (l & 48) | (gg * 4 + r));
#pragma unroll
        for (int df = 0; df < 4; ++df) o[mi][df][r] *= ar;
      }
      // pack P to bf16 pairs: pk0[f]=(r0,r1), pk1[f]=(r2,r3)
      unsigned pk0[4], pk1[4];
#pragma unroll
      for (int f = 0; f < 4; ++f) {
        pk0[f] = cvtpk_bf16(p[f][0], p[f][1]);
        pk1[f] = cvtpk_bf16(p[f][2], p[f][3]);
      }
      // exchange: dest (gg,lrq) word w of ks-frag = pk[2ks+(gg>>1)][w&1]
      // from lane ((gg&1)*2 + (w>>1))*16 + lrq
      int srcA = ((l & 16) << 1) | lrq;
      int srcB = srcA + 16;
      bool fhi = (l & 32) != 0;
#pragma unroll
      for (int ks = 0; ks < 2; ++ks) {
        unsigned a0 = (unsigned)__shfl((int)pk0[2 * ks], srcA);
        unsigned b0 = (unsigned)__shfl((int)pk0[2 * ks + 1], srcA);
        unsigned a1 = (unsigned)__shfl((int)pk1[2 * ks], srcA);
        unsigned b1 = (unsigned)__shfl((int)pk1[2 * ks + 1], srcA);
        unsigned a2 = (unsigned)__shfl((int)pk0[2 * ks], srcB);
        unsigned b2 = (unsigned)__shfl((int)pk0[2 * ks + 1], srcB);
        unsigned a3 = (unsigned)__shfl((int)pk1[2 * ks], srcB);
        unsigned b3 = (unsigned)__shfl((int)pk1[2 * ks + 1], srcB);
        union { unsigned u[4]; bf16x8 v; } pw;
        pw.u[0] = fhi ? b0 : a0;
        pw.u[1] = fhi ? b1 : a1;
        pw.u[2] = fhi ? b2 : a2;
        pw.u[3] = fhi ? b3 : a3;
        paM[mi][ks] = pw.v;
      }
    }

    // ---- O += P V ----
    {
      bf16x8 vb[4][2];
#pragma unroll
      for (int df = 0; df < 4; ++df)
#pragma unroll
        for (int ks = 0; ks < 2; ++ks) {
          int row = df * 16 + lrq;
          vb[df][ks] = *(const bf16x8*)(curb + 8192 + row * 128 +
                                        ((ks * 64 + gg * 16) ^ ((row & 7) << 4)));
        }
#pragma unroll
      for (int mi = 0; mi < 2; ++mi)
#pragma unroll
        for (int df = 0; df < 4; ++df) {
          o[mi][df] = __builtin_amdgcn_mfma_f32_16x16x32_bf16(paM[mi][0], vb[df][0], o[mi][df], 0, 0, 0);
          o[mi][df] = __builtin_amdgcn_mfma_f32_16x16x32_bf16(paM[mi][1], vb[df][1], o[mi][df], 0, 0, 0);
        }
    }
    __builtin_amdgcn_sched_barrier(0);
    asm volatile("s_waitcnt lgkmcnt(0)" ::: "memory");
    __builtin_amdgcn_s_barrier();
  }
#undef STAGE_KV

  // epilogue: normalize, split hi/lo, write Osp [hi | lo | hi]
#pragma unroll
  for (int mi = 0; mi < 2; ++mi) {
    float invm = 1.0f / lrun[mi];
#pragma unroll
    for (int r = 0; r < 4; ++r) {
      float inv = __shfl(invm, (l & 48) | (gg * 4 + r));
#pragma unroll
      for (int df = 0; df < 4; ++df) {
        float v = o[mi][df][r] * inv;
        long token = tok0 + q0 + mi * 16 + gg * 4 + r;
        int c = h * HD_ + df * 16 + lrq;
        unsigned short hi = f2bf(v);
        unsigned short lo = f2bf(v - bf2f(hi));
        Osp[token * N1_ + c] = hi;
        Osp[token * N1_ + 768 + c] = lo;
        Osp[token * N1_ + 1536 + c] = hi;
      }
    }
  }
}

// =====================================================================
extern "C" void kernel_launch(void* const* d_in, const int* in_sizes, int n_in,
                              void* d_out, int out_size, void* d_ws, size_t ws_size,
                              hipStream_t stream) {
  const float* x    = (const float*)d_in[0];
  const float* Wqkv = (const float*)d_in[1];
  const float* bqkv = (const float*)d_in[2];
  const float* Wout = (const float*)d_in[3];
  const float* bout = (const float*)d_in[4];

  char* ws = (char*)d_ws;
  unsigned short* qkvb  = (unsigned short*)(ws);                 // 75,497,472 B
  unsigned short* Osp   = (unsigned short*)(ws + 75497472L);     // 75,497,472 B
  unsigned short* xb    = (unsigned short*)(ws + 150994944L);    // 25,165,824 B
  unsigned short* Vt    = (unsigned short*)(ws + 150994944L);    // alias of xb
  unsigned short* WqkvT = (unsigned short*)(ws + 176160768L);    //  3,538,944 B
  unsigned short* Wt3   = (unsigned short*)(ws + 179699712L);    //  3,538,944 B

  k_cvt_x<<<6144, 256, 0, stream>>>(x, xb);
  k_prep_wqkvT<<<864, 256, 0, stream>>>(Wqkv, WqkvT);
  k_prep_wout<<<288, 256, 0, stream>>>(Wout, Wt3);
  gemm_bf16<1><<<128 * 18, 256, 0, stream>>>(xb, WqkvT, bqkv, (void*)qkvb, 768, 2304);
  k_transposeV2<<<1536, 256, 0, stream>>>(qkvb, Vt);
  attn_fused<<<1536, 256, 0, stream>>>(qkvb, Vt, Osp);
  gemm_bf16<3><<<128 * 6, 256, 0, stream>>>(Osp, Wt3, bout, d_out, 2304, 768);
}

// Round 3
// 262.691 us; speedup vs baseline: 1.3769x; 1.0850x over previous
//
#include <hip/hip_runtime.h>
#include <hip/hip_bf16.h>

// Problem constants
#define B_   16
#define N_   1024
#define C_   768
#define H_   12
#define HD_  64
#define M_   16384   // B*N tokens
#define N1_  2304    // 3*C
#define NEG_BIG (-1e30f)
#define LOG2E 1.4426950408889634f

typedef __attribute__((ext_vector_type(8))) short bf16x8;   // 8 bf16 = 4 VGPR
typedef __attribute__((ext_vector_type(4))) float f32x4;
typedef __attribute__((ext_vector_type(16))) float f32x16;

// ---- bf16 helpers via raw bits ----
__device__ __forceinline__ unsigned short f2bf(float f) {
  unsigned int u = __float_as_uint(f);
  u = u + 0x7fffu + ((u >> 16) & 1u);   // round-to-nearest-even
  return (unsigned short)(u >> 16);
}
__device__ __forceinline__ float bf2f(unsigned short h) {
  return __uint_as_float(((unsigned int)h) << 16);
}
__device__ __forceinline__ unsigned int cvtpk_bf16(float a, float b) {
  unsigned int r;
  asm("v_cvt_pk_bf16_f32 %0, %1, %2" : "=v"(r) : "v"(a), "v"(b));
  return r;  // lo16 = bf16(a), hi16 = bf16(b)
}
__device__ __forceinline__ float exp2_asm(float x) {
  float r;
  asm("v_exp_f32 %0, %1" : "=v"(r) : "v"(x));
  return r;
}

__device__ __forceinline__ void gload_lds16(const void* g, void* l) {
  __builtin_amdgcn_global_load_lds(
      (const __attribute__((address_space(1))) void*)g,
      (__attribute__((address_space(3))) void*)l, 16, 0, 0);
}

// =====================================================================
// Prep kernels
// =====================================================================

__global__ __launch_bounds__(256) void k_cvt_x(const float* __restrict__ x,
                                               unsigned short* __restrict__ xb) {
  long i = ((long)blockIdx.x * 256 + threadIdx.x) * 8;
  float4 a = *(const float4*)(x + i);
  float4 b = *(const float4*)(x + i + 4);
  bf16x8 v;
  v[0] = (short)f2bf(a.x); v[1] = (short)f2bf(a.y);
  v[2] = (short)f2bf(a.z); v[3] = (short)f2bf(a.w);
  v[4] = (short)f2bf(b.x); v[5] = (short)f2bf(b.y);
  v[6] = (short)f2bf(b.z); v[7] = (short)f2bf(b.w);
  *(bf16x8*)(xb + i) = v;
}

__global__ __launch_bounds__(256) void k_prep_wqkvT(const float* __restrict__ W,
                                                    unsigned short* __restrict__ Wt) {
  int tid = blockIdx.x * 256 + threadIdx.x;   // 96*2304 threads
  int n  = tid % N1_;
  int kc = tid / N1_;                          // 0..95
  bf16x8 v;
#pragma unroll
  for (int j = 0; j < 8; ++j)
    v[j] = (short)f2bf(W[(long)(kc * 8 + j) * N1_ + n]);
  *(bf16x8*)(Wt + (long)n * C_ + kc * 8) = v;
}

__global__ __launch_bounds__(256) void k_prep_wout(const float* __restrict__ W,
                                                   unsigned short* __restrict__ Wt3) {
  int tid = blockIdx.x * 256 + threadIdx.x;   // 96*768 threads
  int n  = tid % C_;
  int kc = tid / C_;                           // 0..95
  bf16x8 hi, lo;
#pragma unroll
  for (int j = 0; j < 8; ++j) {
    float wv = W[(long)(kc * 8 + j) * C_ + n];
    unsigned short h = f2bf(wv);
    hi[j] = (short)h;
    lo[j] = (short)f2bf(wv - bf2f(h));
  }
  unsigned short* base = Wt3 + (long)n * N1_ + kc * 8;
  *(bf16x8*)(base)        = hi;
  *(bf16x8*)(base + 768)  = hi;
  *(bf16x8*)(base + 1536) = lo;
}

// Transpose V region of qkvb into Vt [bh][64 d][1024 n] via LDS tile.
__global__ __launch_bounds__(256) void k_transposeV2(const unsigned short* __restrict__ qkvb,
                                                     unsigned short* __restrict__ Vt) {
  __shared__ unsigned char lt[16384];   // [64 d][128 n] bf16, swizzled
  int wid = (blockIdx.x & 7) * 192 + (blockIdx.x >> 3);   // XCD-chunked
  int bh = wid >> 3, nb = wid & 7;
  int b = bh / H_, h = bh % H_;
  long tok0 = (long)b * N_ + nb * 128;
  int t = threadIdx.x;
  int d0 = (t & 7) * 8;
#pragma unroll
  for (int it = 0; it < 4; ++it) {
    int nl = it * 32 + (t >> 3);
    bf16x8 v = *(const bf16x8*)(qkvb + (tok0 + nl) * N1_ + 1536 + h * HD_ + d0);
#pragma unroll
    for (int j = 0; j < 8; ++j) {
      int d = d0 + j;
      *(unsigned short*)(lt + d * 256 + ((nl * 2) ^ (((d >> 3) & 7) << 4))) =
          (unsigned short)v[j];
    }
  }
  __syncthreads();
  int l = t & 63, wv = t >> 6;
  int p = l & 1;
  int dbase = ((l >> 1) & 7) * 8 + (l >> 4) * 2;
#pragma unroll
  for (int rr = 0; rr < 4; ++rr) {
    int d = dbase + (rr & 1);
    int n0 = wv * 32 + (rr >> 1) * 16 + p * 8;
    bf16x8 v = *(const bf16x8*)(lt + d * 256 + ((n0 * 2) ^ (((d >> 3) & 7) << 4)));
    *(bf16x8*)(Vt + ((long)bh * HD_ + d) * N_ + nb * 128 + n0) = v;
  }
}

// =====================================================================
// GEMM: C[M,N] = A[M,K](bf16) * Bt[N,K]^T(bf16) + bias   (unchanged)
// =====================================================================
template <int STAGE>
__global__ __launch_bounds__(256)
void gemm_bf16(const unsigned short* __restrict__ A,
               const unsigned short* __restrict__ Bt,
               const float* __restrict__ bias,
               void* __restrict__ out, int Kdim, int Ndim) {
  __shared__ unsigned char lds[32768];   // A tile 16K | B tile 16K
  const int t = threadIdx.x;
  const int l = t & 63, w = t >> 6;
  const int g = l >> 4, lr = l & 15;
  const int NB = Ndim >> 7;
  const int mb = blockIdx.x / NB, nb = blockIdx.x % NB;
  const long m0 = (long)mb << 7, n0 = (long)nb << 7;
  const int wm = w >> 1, wn = w & 1;

  f32x4 acc[4][4];
  const f32x4 zz = {0.f, 0.f, 0.f, 0.f};
#pragma unroll
  for (int i = 0; i < 4; ++i)
#pragma unroll
    for (int j = 0; j < 4; ++j) acc[i][j] = zz;

  int srow[4], sx[4];
#pragma unroll
  for (int i = 0; i < 4; ++i) {
    int s = i * 4096 + t * 16;
    int row = s >> 7;
    srow[i] = row;
    sx[i] = (s & 127) ^ ((row & 7) << 4);
  }
  const char* Ab = (const char*)A;
  const char* Bb = (const char*)Bt;
  const int wbase = (t & 192) * 16;

  for (int kt = 0; kt < Kdim; kt += 64) {
#pragma unroll
    for (int i = 0; i < 4; ++i) {
      const char* src = Ab + ((m0 + srow[i]) * Kdim + kt) * 2 + sx[i];
      gload_lds16(src, (void*)(lds + i * 4096 + wbase));
    }
#pragma unroll
    for (int i = 0; i < 4; ++i) {
      const char* src = Bb + ((n0 + srow[i]) * Kdim + kt) * 2 + sx[i];
      gload_lds16(src, (void*)(lds + 16384 + i * 4096 + wbase));
    }
    __syncthreads();
#pragma unroll
    for (int ks = 0; ks < 2; ++ks) {
      bf16x8 af[4], bfr[4];
#pragma unroll
      for (int mi = 0; mi < 4; ++mi) {
        int row = wm * 64 + mi * 16 + lr;
        int off = row * 128 + ((ks * 64 + g * 16) ^ ((row & 7) << 4));
        af[mi] = *(const bf16x8*)(lds + off);
      }
#pragma unroll
      for (int ni = 0; ni < 4; ++ni) {
        int row = wn * 64 + ni * 16 + lr;
        int off = 16384 + row * 128 + ((ks * 64 + g * 16) ^ ((row & 7) << 4));
        bfr[ni] = *(const bf16x8*)(lds + off);
      }
#pragma unroll
      for (int mi = 0; mi < 4; ++mi)
#pragma unroll
        for (int ni = 0; ni < 4; ++ni)
          acc[mi][ni] = __builtin_amdgcn_mfma_f32_16x16x32_bf16(
              af[mi], bfr[ni], acc[mi][ni], 0, 0, 0);
    }
    __syncthreads();
  }

#pragma unroll
  for (int ni = 0; ni < 4; ++ni) {
    int col = (int)n0 + wn * 64 + ni * 16 + lr;
    float bv = bias[col];
    if (STAGE == 1) {
      // pre-scale Q by (1/sqrt(HD)) * log2(e)  -> softmax runs in exp2 domain
      float sc = (col < 768) ? 0.125f * LOG2E : 1.0f;
      unsigned short* o = (unsigned short*)out;
#pragma unroll
      for (int mi = 0; mi < 4; ++mi)
#pragma unroll
        for (int r = 0; r < 4; ++r) {
          long rowm = m0 + wm * 64 + mi * 16 + g * 4 + r;
          o[rowm * N1_ + col] = f2bf((acc[mi][ni][r] + bv) * sc);
        }
    } else {
      float* o = (float*)out;
#pragma unroll
      for (int mi = 0; mi < 4; ++mi)
#pragma unroll
        for (int r = 0; r < 4; ++r) {
          long rowm = m0 + wm * 64 + mi * 16 + g * 4 + r;
          o[rowm * C_ + col] = acc[mi][ni][r] + bv;
        }
    }
  }
}

// =====================================================================
// Fused flash attention, 32x32x16 MFMA, fully-transposed form.
// S^T = mfma(K, Q): lane (q=l&31, hi=l>>5) holds 32 scores of its OWN q.
// O^T = mfma(V^T, P): lane holds 32 d-values of its OWN q.
// Softmax entirely in-lane (+1 shfl_xor(32) for max & sum). P exchange =
// 16 cvt_pk + 8 permlane32_swap. Defer-max rescale (THR=8, log2 units).
// 4 waves x 32 q = 128 q / block; KV tiles 64, dbuf + counted vmcnt.
// =====================================================================
__global__ __launch_bounds__(256, 3)
void attn_fused(const unsigned short* __restrict__ qkvb,
                const unsigned short* __restrict__ Vt,
                unsigned short* __restrict__ Osp) {
  __shared__ unsigned char lds[32768];  // 2 x (K 8K | V 8K)
  const int t = threadIdx.x, l = t & 63, w = t >> 6;
  const int q32 = l & 31;              // lane's q within wave block
  const int hi = l >> 5;               // lane half
  const int hi16 = hi * 16;            // byte offset of k-subblock in LDS reads
  // XCD-chunked swizzle: 8 q-blocks of one head share one XCD's L2
  const int wid = (blockIdx.x & 7) * 192 + (blockIdx.x >> 3);
  const int bh = wid >> 3, qb = wid & 7;
  const int b = bh / H_, h = bh % H_;
  const long tok0 = (long)b * N_;
  const int q0 = qb * 128 + w * 32;
  const long mytok = tok0 + q0 + q32;

  // Q B-fragments: lane (q, hi) holds c = cs*16 + hi*8 + j  (pre-scaled)
  bf16x8 qa[4];
#pragma unroll
  for (int cs = 0; cs < 4; ++cs)
    qa[cs] = *(const bf16x8*)(qkvb + mytok * N1_ + h * HD_ + cs * 16 + hi * 8);

  const f32x16 zz16 = {0.f};
  f32x16 o0 = zz16, o1 = zz16;   // O^T: d 0..31 / 32..63 for lane's q
  float mrun = NEG_BIG, lrun = 0.f;

  const int row0 = q32, row1 = 32 + q32;
  const int swz0 = (row0 & 7) << 4;   // == (row1&7)<<4

  // staging decode (slot = t*16 within 4K sub-tile; source pre-swizzled)
  const int sxs = ((t & 7) * 16) ^ (((t >> 3) & 7) << 4);
  const int wbase = (t & 192) * 16;
  const char* Vg = (const char*)(Vt + (long)bh * HD_ * N_);
  const char* Kg = (const char*)qkvb + ((tok0)*N1_ + C_ + h * HD_) * 2;

#define STAGE_KV(kv0, buf)                                                  \
  {                                                                         \
    _Pragma("unroll")                                                       \
    for (int i = 0; i < 2; ++i) {                                           \
      int row = i * 32 + (t >> 3);                                          \
      gload_lds16(Kg + ((long)(kv0 + row) * N1_) * 2 + sxs,                 \
                  (void*)((buf) + i * 4096 + wbase));                       \
    }                                                                       \
    _Pragma("unroll")                                                       \
    for (int i = 0; i < 2; ++i) {                                           \
      int row = i * 32 + (t >> 3);                                          \
      gload_lds16(Vg + ((long)row * N_ + (kv0)) * 2 + sxs,                  \
                  (void*)((buf) + 8192 + i * 4096 + wbase));                \
    }                                                                       \
  }

  STAGE_KV(0, lds);

#pragma unroll 2
  for (int tt = 0; tt < 16; ++tt) {
    unsigned char* curb = lds + (tt & 1) * 16384;
    unsigned char* nxtb = lds + ((tt & 1) ^ 1) * 16384;
    if (tt < 15) {
      STAGE_KV((tt + 1) * 64, nxtb);
      asm volatile("s_waitcnt vmcnt(4)" ::: "memory");
    } else {
      asm volatile("s_waitcnt vmcnt(0)" ::: "memory");
    }
    __builtin_amdgcn_s_barrier();
    __builtin_amdgcn_sched_barrier(0);

    // ---- S^T = mfma(K_A, Q_B): two 32-k tiles ----
    f32x16 sa0 = zz16, sa1 = zz16;
#pragma unroll
    for (int cs = 0; cs < 4; ++cs) {
      bf16x8 kf0 = *(const bf16x8*)(curb + row0 * 128 + ((cs * 32 + hi16) ^ swz0));
      bf16x8 kf1 = *(const bf16x8*)(curb + row1 * 128 + ((cs * 32 + hi16) ^ swz0));
      sa0 = __builtin_amdgcn_mfma_f32_32x32x16_bf16(kf0, qa[cs], sa0, 0, 0, 0);
      sa1 = __builtin_amdgcn_mfma_f32_32x32x16_bf16(kf1, qa[cs], sa1, 0, 0, 0);
    }

    // ---- in-lane online softmax (log2 domain) ----
    float mx = sa0[0];
#pragma unroll
    for (int r = 1; r < 16; ++r) mx = fmaxf(mx, sa0[r]);
#pragma unroll
    for (int r = 0; r < 16; ++r) mx = fmaxf(mx, sa1[r]);
    mx = fmaxf(mx, __shfl_xor(mx, 32));
    if (!__all(mx <= mrun + 8.f)) {           // defer-max: rescale only on growth
      float mn = fmaxf(mrun, mx);
      float al = exp2_asm(mrun - mn);
      mrun = mn;
      lrun *= al;
      o0 *= al;
      o1 *= al;
    }
    float rs = 0.f;
    unsigned pk[2][4][2];
#pragma unroll
    for (int g = 0; g < 4; ++g) {
      float p0 = exp2_asm(sa0[4 * g + 0] - mrun);
      float p1 = exp2_asm(sa0[4 * g + 1] - mrun);
      float p2 = exp2_asm(sa0[4 * g + 2] - mrun);
      float p3 = exp2_asm(sa0[4 * g + 3] - mrun);
      rs += (p0 + p1) + (p2 + p3);
      pk[0][g][0] = cvtpk_bf16(p0, p1);
      pk[0][g][1] = cvtpk_bf16(p2, p3);
    }
#pragma unroll
    for (int g = 0; g < 4; ++g) {
      float p0 = exp2_asm(sa1[4 * g + 0] - mrun);
      float p1 = exp2_asm(sa1[4 * g + 1] - mrun);
      float p2 = exp2_asm(sa1[4 * g + 2] - mrun);
      float p3 = exp2_asm(sa1[4 * g + 3] - mrun);
      rs += (p0 + p1) + (p2 + p3);
      pk[1][g][0] = cvtpk_bf16(p0, p1);
      pk[1][g][1] = cvtpk_bf16(p2, p3);
    }
    rs += __shfl_xor(rs, 32);
    lrun += rs;

    // ---- P^T -> B-operand fragments via permlane32_swap ----
    bf16x8 pb[4];
#pragma unroll
    for (int tk = 0; tk < 2; ++tk)
#pragma unroll
      for (int par = 0; par < 2; ++par) {
        unsigned a0 = pk[tk][2 * par][0], b0 = pk[tk][2 * par + 1][0];
        unsigned a1 = pk[tk][2 * par][1], b1 = pk[tk][2 * par + 1][1];
        asm("v_permlane32_swap_b32 %0, %1" : "+v"(a0), "+v"(b0));
        asm("v_permlane32_swap_b32 %0, %1" : "+v"(a1), "+v"(b1));
        union { unsigned u[4]; bf16x8 v; } pw;
        pw.u[0] = a0; pw.u[1] = a1; pw.u[2] = b0; pw.u[3] = b1;
        pb[2 * tk + par] = pw.v;
      }

    // ---- O^T += mfma(V^T_A, P_B) ----
#pragma unroll
    for (int kb = 0; kb < 4; ++kb) {
      bf16x8 vf0 = *(const bf16x8*)(curb + 8192 + row0 * 128 + ((kb * 32 + hi16) ^ swz0));
      bf16x8 vf1 = *(const bf16x8*)(curb + 8192 + row1 * 128 + ((kb * 32 + hi16) ^ swz0));
      o0 = __builtin_amdgcn_mfma_f32_32x32x16_bf16(vf0, pb[kb], o0, 0, 0, 0);
      o1 = __builtin_amdgcn_mfma_f32_32x32x16_bf16(vf1, pb[kb], o1, 0, 0, 0);
    }
    __builtin_amdgcn_sched_barrier(0);
    asm volatile("s_waitcnt lgkmcnt(0)" ::: "memory");
    __builtin_amdgcn_s_barrier();
  }
#undef STAGE_KV

  // ---- epilogue: normalize lane's own q-row, split hi/lo, paired stores ----
  float inv = 1.0f / lrun;
  unsigned short* obase = Osp + mytok * N1_ + h * HD_;
#pragma unroll
  for (int dt = 0; dt < 2; ++dt) {
#pragma unroll
    for (int rp = 0; rp < 8; ++rp) {
      int r = rp * 2;
      float v0 = (dt ? o1[r] : o0[r]) * inv;
      float v1 = (dt ? o1[r + 1] : o0[r + 1]) * inv;
      unsigned hw = cvtpk_bf16(v0, v1);
      float l0 = v0 - bf2f((unsigned short)(hw & 0xffff));
      float l1 = v1 - bf2f((unsigned short)(hw >> 16));
      unsigned lw = cvtpk_bf16(l0, l1);
      int d = dt * 32 + (r & 3) + 8 * (r >> 2) + 4 * hi;
      *(unsigned*)(obase + d) = hw;
      *(unsigned*)(obase + 768 + d) = lw;
      *(unsigned*)(obase + 1536 + d) = hw;
    }
  }
}

// =====================================================================
extern "C" void kernel_launch(void* const* d_in, const int* in_sizes, int n_in,
                              void* d_out, int out_size, void* d_ws, size_t ws_size,
                              hipStream_t stream) {
  const float* x    = (const float*)d_in[0];
  const float* Wqkv = (const float*)d_in[1];
  const float* bqkv = (const float*)d_in[2];
  const float* Wout = (const float*)d_in[3];
  const float* bout = (const float*)d_in[4];

  char* ws = (char*)d_ws;
  unsigned short* qkvb  = (unsigned short*)(ws);                 // 75,497,472 B
  unsigned short* Osp   = (unsigned short*)(ws + 75497472L);     // 75,497,472 B
  unsigned short* xb    = (unsigned short*)(ws + 150994944L);    // 25,165,824 B
  unsigned short* Vt    = (unsigned short*)(ws + 150994944L);    // alias of xb
  unsigned short* WqkvT = (unsigned short*)(ws + 176160768L);    //  3,538,944 B
  unsigned short* Wt3   = (unsigned short*)(ws + 179699712L);    //  3,538,944 B

  k_cvt_x<<<6144, 256, 0, stream>>>(x, xb);
  k_prep_wqkvT<<<864, 256, 0, stream>>>(Wqkv, WqkvT);
  k_prep_wout<<<288, 256, 0, stream>>>(Wout, Wt3);
  gemm_bf16<1><<<128 * 18, 256, 0, stream>>>(xb, WqkvT, bqkv, (void*)qkvb, 768, 2304);
  k_transposeV2<<<1536, 256, 0, stream>>>(qkvb, Vt);
  attn_fused<<<1536, 256, 0, stream>>>(qkvb, Vt, Osp);
  gemm_bf16<3><<<128 * 6, 256, 0, stream>>>(Osp, Wt3, bout, d_out, 2304, 768);
}